// Round 7
// baseline (337.288 us; speedup 1.0000x reference)
//
#include <hip/hip_runtime.h>
#include <cfloat>
#include <climits>

// Problem constants
#define N_ROWS 65536          // 64*1024 flattened rows
#define DIM 256
#define K_CODES 1024
#define N_ELEM 16777216       // N_ROWS*DIM
#define OUT_LOSS_OFF 16777216
#define OUT_IDX_OFF  16777217

#define ROWS_PB 128           // rows per block (argmin)
#define CT 128                // codes per tile
// Ref computes dists in fp32 with +||x||^2 (~256) -> grid ulp ~3.05e-5; flips
// need exact gap <= ~6.5e-5. Pass-1 (bf16-split MFMA) error ~2e-6..4e-6. Margin
// 1.5e-4 keeps >18x safety. EPS logic needs only |err| << margin - any
// nearest-rounding split qualifies (R5-proven: cvt_pk RNE split, absmax 3.8e-6).
#define EPS_MARGIN 1.5e-4f
#define SHORTLIST_EPS 6e-4f   // covers exact-gap 6.6e-5 + 2*max|x.elo| ~4.2e-4
#define RB 8                  // flagged rows batched per rescore block

// ws layout (bytes)
#define WS_PARTIALS 0         // 1024 double
#define WS_ESQ      8192      // 1024 float
#define WS_IDX      12288     // 65536 int
#define WS_FLAGCNT  274432    // 1 int
#define WS_DONECNT  274436    // 1 int (gather last-block counter)
#define WS_FLAGLIST 274440    // up to 65536 int -> ends 536584
#define WS_EHI      540672    // 1024*256 u16 = 512 KB (row-major, for argmin)
#define WS_ELO      1064960   // 512 KB
#define WS_EHIT     1589248   // 512 KB q-major transpose (for rescore) -> ends 2113536

typedef unsigned short u16;
typedef __attribute__((ext_vector_type(8))) short bf16x8;
typedef __attribute__((ext_vector_type(4))) float f32x4;
typedef union { bf16x8 v; unsigned u[4]; } frag_u;

// ---- async global->LDS 16B (wave-uniform LDS base + lane*16) ----
__device__ __forceinline__ void glds16(const void* g, void* l) {
    __builtin_amdgcn_global_load_lds(
        (const __attribute__((address_space(1))) unsigned int*)g,
        (__attribute__((address_space(3))) unsigned int*)l,
        16, 0, 0);
}

// ---- packed f32->bf16 RNE (2 elements/op); pure asm (no side effects) ----
__device__ __forceinline__ unsigned cvt_pk_bf16(float lo, float hi) {
    unsigned r;
    asm("v_cvt_pk_bf16_f32 %0, %1, %2" : "=v"(r) : "v"(lo), "v"(hi));
    return r;
}

// ---- exact two-term bf16 split of 8 f32 -> (hi8, lo8) fragments ----
// hi = RNE-bf16(x); lf = x - hi (exact, Sterbenz); lo = RNE-bf16(lf).
__device__ __forceinline__ void split8(float4 a, float4 b, bf16x8& h8, bf16x8& l8) {
    frag_u H, L;
    float f0 = a.x, f1 = a.y, f2 = a.z, f3 = a.w;
    float f4 = b.x, f5 = b.y, f6 = b.z, f7 = b.w;
    const float* f[8] = {&f0,&f1,&f2,&f3,&f4,&f5,&f6,&f7};
    #pragma unroll
    for (int p = 0; p < 4; ++p) {
        float xl = *f[2*p], xh = *f[2*p+1];
        unsigned hw = cvt_pk_bf16(xl, xh);
        float hfl = __uint_as_float(hw << 16);
        float hfh = __uint_as_float(hw & 0xffff0000u);
        H.u[p] = hw;
        L.u[p] = cvt_pk_bf16(xl - hfl, xh - hfh);
    }
    h8 = H.v; l8 = L.v;
}

// ---- exact two-term bf16 split (RN, scalar bit version - eprep only) ----
__device__ __forceinline__ void bsplit(float x, u16& h, u16& l) {
    unsigned u = __float_as_uint(x);
    unsigned hb = (u + 0x7fffu + ((u >> 16) & 1u)) >> 16;
    h = (u16)hb;
    float hf = __uint_as_float(hb << 16);
    float lf = x - hf;                       // exact
    unsigned u2 = __float_as_uint(lf);
    l = (u16)((u2 + 0x7fffu + ((u2 >> 16) & 1u)) >> 16);
}

// ---- numpy fp32 pairwise sum-of-squares over 256 elements (round-3 proven) ----
__device__ __forceinline__ float np_pairwise_sumsq(const float* __restrict__ a) {
    float half[2];
    #pragma unroll
    for (int h = 0; h < 2; ++h) {
        const float* p = a + h * 128;
        float r[8];
        #pragma unroll
        for (int j = 0; j < 8; ++j) r[j] = __fmul_rn(p[j], p[j]);
        for (int i = 8; i < 128; i += 8) {
            #pragma unroll
            for (int j = 0; j < 8; ++j)
                r[j] = __fadd_rn(r[j], __fmul_rn(p[i + j], p[i + j]));
        }
        half[h] = __fadd_rn(__fadd_rn(__fadd_rn(r[0], r[1]), __fadd_rn(r[2], r[3])),
                            __fadd_rn(__fadd_rn(r[4], r[5]), __fadd_rn(r[6], r[7])));
    }
    return __fadd_rn(half[0], half[1]);
}

// ---- fused e-prep: esplit (blocks 0..255) + esq (blocks 256..259) + counters ----
// ehiT layout: [qid 0..31][code 0..1023][8 u16], qid = 16B-chunk of the dim axis.
__launch_bounds__(256)
__global__ void eprep_kernel(const float* __restrict__ e, u16* __restrict__ ehi,
                             u16* __restrict__ elo, u16* __restrict__ ehiT,
                             float* __restrict__ esqOut, int* __restrict__ flagCnt,
                             int* __restrict__ doneCnt) {
    const int b = blockIdx.x;
    if (b < 256) {
        int i4 = b * 256 + threadIdx.x;            // 0..65535
        float4 v = ((const float4*)e)[i4];
        ushort4 h, l;
        bsplit(v.x, h.x, l.x); bsplit(v.y, h.y, l.y);
        bsplit(v.z, h.z, l.z); bsplit(v.w, h.w, l.w);
        ((ushort4*)ehi)[i4] = h;
        ((ushort4*)elo)[i4] = l;
        int c = i4 >> 6;
        int f4 = i4 & 63;
        int qid = f4 >> 1;
        ((ushort4*)ehiT)[((size_t)qid * 1024 + c) * 2 + (f4 & 1)] = h;
    } else {
        if (b == 256 && threadIdx.x == 0) { *flagCnt = 0; *doneCnt = 0; }
        int c = (b - 256) * 256 + threadIdx.x;
        if (c < K_CODES) esqOut[c] = np_pairwise_sumsq(e + c * DIM);
    }
}

// ---------------- Kernel A: split-bf16 MFMA distance + argmin ----------------
// R1-proven schedule+compute: 8 waves (512 thr) in 4x2 over a 128x128 tile
// (wave = 32 rows x 64 codes); 66KB LDS -> 2 blocks/CU = 16 waves/CU (R3:
// dbuf at 1 block/CU regressed - __syncthreads drains vmcnt(0) including
// just-issued LDS prefetch; do not pipeline without counted-vmcnt barriers).
// R7: x chunk-ahead REGISTER prefetch. x is ct-invariant, so chunk s+1's x
// loads are issued at the TOP of chunk s's compute phase - into VGPRs, not
// LDS, so the barrier vmcnt(0) drain lands AFTER the ~500cyc MFMA phase has
// covered the load latency. Stage phase becomes: split(regs)+ds_write+e-DMA,
// no global-load wait on its critical path (R6's regression vs R1 was this
// serial load-wait inside every stage). +16 VGPRs (~80 total, <128 cap).
// LDS tiles [128][64] u16; 16B-block slot jb holds source block jb^(row&7).
__launch_bounds__(512, 4)
__global__ void argmin_kernel(const float* __restrict__ x,
                              const u16* __restrict__ ehi, const u16* __restrict__ elo,
                              const float* __restrict__ esq, int* __restrict__ wsIdx,
                              int* __restrict__ flagCnt, int* __restrict__ flagList) {
    __shared__ __align__(16) unsigned char lds[65536];
    __shared__ float esq_s[CT];
    u16* xhiS = (u16*)lds;              // [128][64] swizzled, 16 KB
    u16* xloS = (u16*)(lds + 16384);
    u16* ehiS = (u16*)(lds + 32768);
    u16* eloS = (u16*)(lds + 49152);

    const int t = threadIdx.x;
    const int w = t >> 6;               // wave 0..7
    const int l = t & 63;
    const int lane15 = l & 15;
    const int quad = l >> 4;            // 0..3
    const int rowBase = blockIdx.x * ROWS_PB;
    const int wr = w >> 1;              // 0..3: 32-row group
    const int wc = w & 1;               // 0..1: 64-code group

    float bv[8], sv[8]; int bi[8];
    #pragma unroll
    for (int i = 0; i < 8; ++i) { bv[i] = FLT_MAX; sv[i] = FLT_MAX; bi[i] = INT_MAX; }

    // e staging roles (glds16): waves 4,5 -> ehi halves, waves 6,7 -> elo halves.
    const int sub8 = l >> 3;            // e: row-in-group-of-8
    const int jb8 = l & 7;              // e: 16B-block slot in 128B row
    const int sb8 = jb8 ^ sub8;         // e: swizzled source block
    const u16* srcE = (w < 6) ? ehi : elo;
    u16* dstE = (w < 6) ? ehiS : eloS;
    const int halfE = w & 1;

    // x staging decomposition: 1024 groups of 8 floats per chunk; 2 per thread.
    // group g: row r=g>>3, dest slot jb=g&7, source block sb=jb^(r&7).
    const int g0 = t;                   // rows 0..63
    const int g1 = 512 + t;             // rows 64..127
    const int r0 = g0 >> 3, jb0 = g0 & 7, sb0 = jb0 ^ (r0 & 7);
    const int r1 = g1 >> 3, jb1 = g1 & 7, sb1 = jb1 ^ (r1 & 7);
    const float* xp0 = x + (size_t)(rowBase + r0) * 256 + sb0 * 8;
    const float* xp1 = x + (size_t)(rowBase + r1) * 256 + sb1 * 8;

    // prologue: prefetch x chunk 0 into registers
    float4 pva0, pvb0, pva1, pvb1;
    pva0 = ((const float4*)xp0)[0]; pvb0 = ((const float4*)xp0)[1];
    pva1 = ((const float4*)xp1)[0]; pvb1 = ((const float4*)xp1)[1];

    for (int ct = 0; ct < 8; ++ct) {
        const int ctBase = ct * CT;
        __syncthreads();                          // prior epilogue/LDS reads done
        if (t < CT) esq_s[t] = esq[ctBase + t];

        f32x4 acc[2][4];
        #pragma unroll
        for (int ti = 0; ti < 2; ++ti)
            #pragma unroll
            for (int tj = 0; tj < 4; ++tj) acc[ti][tj] = (f32x4){0.f, 0.f, 0.f, 0.f};

        for (int ch = 0; ch < 4; ++ch) {
            __syncthreads();
            // stage: split prefetched x regs -> LDS; e via DMA (no load wait here)
            {
                bf16x8 h8, l8;
                split8(pva0, pvb0, h8, l8);
                *(bf16x8*)(xhiS + r0 * 64 + jb0 * 8) = h8;
                *(bf16x8*)(xloS + r0 * 64 + jb0 * 8) = l8;
                split8(pva1, pvb1, h8, l8);
                *(bf16x8*)(xhiS + r1 * 64 + jb1 * 8) = h8;
                *(bf16x8*)(xloS + r1 * 64 + jb1 * 8) = l8;
            }
            if (w >= 4) {
                #pragma unroll
                for (int i = 0; i < 8; ++i) {
                    int r = halfE * 64 + i * 8 + sub8;
                    glds16(srcE + (size_t)(ctBase + r) * 256 + ch * 64 + sb8 * 8,
                           dstE + halfE * 4096 + i * 512);
                }
            }
            __syncthreads();

            // issue next-chunk x prefetch (registers; latency hidden under MFMA;
            // wraps harmlessly to chunk 0 on the final iteration)
            {
                const int chn = (ch + 1) & 3;
                pva0 = ((const float4*)(xp0 + chn * 64))[0];
                pvb0 = ((const float4*)(xp0 + chn * 64))[1];
                pva1 = ((const float4*)(xp1 + chn * 64))[0];
                pvb1 = ((const float4*)(xp1 + chn * 64))[1];
            }

            #pragma unroll
            for (int kk = 0; kk < 2; ++kk) {      // two 32-wide k-steps
                bf16x8 ah[2], al4[2], bh[4], bl[4];
                const int blk = kk * 4 + quad;    // 16B-block index in row
                #pragma unroll
                for (int ti = 0; ti < 2; ++ti) {
                    int r = wr * 32 + ti * 16 + lane15;
                    int off = r * 64 + ((blk ^ (r & 7)) * 8);
                    ah[ti]  = *(const bf16x8*)(xhiS + off);
                    al4[ti] = *(const bf16x8*)(xloS + off);
                }
                #pragma unroll
                for (int tj = 0; tj < 4; ++tj) {
                    int r = wc * 64 + tj * 16 + lane15;
                    int off = r * 64 + ((blk ^ (r & 7)) * 8);
                    bh[tj] = *(const bf16x8*)(ehiS + off);
                    bl[tj] = *(const bf16x8*)(eloS + off);
                }
                #pragma unroll
                for (int ti = 0; ti < 2; ++ti)
                    #pragma unroll
                    for (int tj = 0; tj < 4; ++tj) {
                        acc[ti][tj] = __builtin_amdgcn_mfma_f32_16x16x32_bf16(al4[ti], bh[tj], acc[ti][tj], 0, 0, 0);
                        acc[ti][tj] = __builtin_amdgcn_mfma_f32_16x16x32_bf16(ah[ti], bl[tj], acc[ti][tj], 0, 0, 0);
                        acc[ti][tj] = __builtin_amdgcn_mfma_f32_16x16x32_bf16(ah[ti], bh[tj], acc[ti][tj], 0, 0, 0);
                    }
            }
        }

        // epilogue: s = ||e||^2 - 2*dot. D-layout: row(M)=quad*4+reg, col(N)=lane&15.
        #pragma unroll
        for (int tj = 0; tj < 4; ++tj) {
            int cLoc = wc * 64 + tj * 16 + lane15;
            float cs = esq_s[cLoc];
            int c = ctBase + cLoc;
            #pragma unroll
            for (int ti = 0; ti < 2; ++ti)
                #pragma unroll
                for (int r4 = 0; r4 < 4; ++r4) {
                    int slot = ti * 4 + r4;
                    float s = fmaf(-2.0f, acc[ti][tj][r4], cs);
                    if (s < bv[slot]) {           // candidates ascend in c
                        sv[slot] = bv[slot]; bv[slot] = s; bi[slot] = c;
                    } else if (s < sv[slot]) {
                        sv[slot] = s;
                    }
                }
        }
    }

    // ---- final cross-contributor top-2 merge via LDS (reuses tile memory) ----
    // stride 33 floats: bank = (row+k)%32 -> conflict-free (round-6 proven).
    __syncthreads();
    float* bvA = (float*)lds;                     // [128 rows][33]
    float* svA = (float*)(lds + 16896);
    int*   biA = (int*)(lds + 33792);
    const int contrib = wc * 16 + lane15;         // 0..31
    #pragma unroll
    for (int slot = 0; slot < 8; ++slot) {
        int m = wr * 32 + (slot >> 2) * 16 + quad * 4 + (slot & 3);
        bvA[m * 33 + contrib] = bv[slot];
        svA[m * 33 + contrib] = sv[slot];
        biA[m * 33 + contrib] = bi[slot];
    }
    __syncthreads();

    if (t < ROWS_PB) {
        float bb = FLT_MAX, ss = FLT_MAX;
        int ii = INT_MAX;
        for (int k = 0; k < 32; ++k) {
            float v  = bvA[t * 33 + k];
            int   id = biA[t * 33 + k];
            float s2 = svA[t * 33 + k];
            if (v < bb || (v == bb && id < ii)) {
                ss = fminf(bb, s2);
                bb = v; ii = id;
            } else {
                ss = fminf(ss, v);
            }
        }
        int row = rowBase + t;
        wsIdx[row] = ii;
        if (ss - bb < EPS_MARGIN) {
            int p = atomicAdd(flagCnt, 1);
            flagList[p] = row;
        }
    }
}

// ------- Kernel A2: flagged-row rescore, RB rows batched per block -------
// Phase A: bf16-hi fp32 scores over all 1024 codes via q-major ehiT
// (coalesced; each ehi byte read once per 8 rows) -> per-row shortlist within
// SHORTLIST_EPS of min. Phase B: numpy-emulated quantized score (round-3/4
// proven formula) on shortlist; lexicographic (s, idx) argmin.
__launch_bounds__(256)
__global__ void rescore_kernel(const float* __restrict__ x, const float* __restrict__ e,
                               const u16* __restrict__ ehiT, const float* __restrict__ esq,
                               int* __restrict__ wsIdx, const int* __restrict__ flagCnt,
                               const int* __restrict__ flagList) {
    __shared__ __align__(16) float xsh[RB][DIM];      // 8 KB
    __shared__ float Ash[RB];
    __shared__ float minsh[RB][256];                  // 8 KB
    __shared__ float thrsh[RB];
    __shared__ int scnt[RB];
    __shared__ int slist[RB][32];
    __shared__ float sres[RB][32];
    const int t = threadIdx.x;
    const int cnt = *flagCnt;
    const int ngroups = (cnt + RB - 1) / RB;
    for (int g = blockIdx.x; g < ngroups; g += gridDim.x) {
        const int base = g * RB;
        const int nr = (cnt - base < RB) ? (cnt - base) : RB;
        __syncthreads();                               // protect reuse across groups
        #pragma unroll
        for (int r = 0; r < RB; ++r)
            xsh[r][t] = (r < nr) ? x[(size_t)flagList[base + r] * DIM + t] : 0.0f;
        if (t < RB) scnt[t] = 0;
        __syncthreads();
        if (t < RB) Ash[t] = np_pairwise_sumsq(xsh[t]);

        // phase A: sA[j][r] = dot(x_r, ehi_c), c = j*256+t
        float sA[4][RB];
        #pragma unroll
        for (int j = 0; j < 4; ++j)
            #pragma unroll
            for (int r = 0; r < RB; ++r) sA[j][r] = 0.0f;

        const uint4* eT4 = (const uint4*)ehiT;
        for (int q = 0; q < 32; ++q) {
            float4 xq[RB][2];
            #pragma unroll
            for (int r = 0; r < RB; ++r) {             // broadcast LDS reads
                xq[r][0] = ((const float4*)xsh[r])[2 * q];
                xq[r][1] = ((const float4*)xsh[r])[2 * q + 1];
            }
            #pragma unroll
            for (int j = 0; j < 4; ++j) {
                uint4 uv = eT4[(size_t)q * 1024 + j * 256 + t];   // coalesced
                float e0 = __uint_as_float(uv.x << 16);
                float e1 = __uint_as_float(uv.x & 0xffff0000u);
                float e2 = __uint_as_float(uv.y << 16);
                float e3 = __uint_as_float(uv.y & 0xffff0000u);
                float e4v = __uint_as_float(uv.z << 16);
                float e5 = __uint_as_float(uv.z & 0xffff0000u);
                float e6 = __uint_as_float(uv.w << 16);
                float e7 = __uint_as_float(uv.w & 0xffff0000u);
                #pragma unroll
                for (int r = 0; r < RB; ++r) {
                    float d0 = sA[j][r];
                    d0 = fmaf(e0, xq[r][0].x, d0);
                    d0 = fmaf(e1, xq[r][0].y, d0);
                    d0 = fmaf(e2, xq[r][0].z, d0);
                    d0 = fmaf(e3, xq[r][0].w, d0);
                    d0 = fmaf(e4v, xq[r][1].x, d0);
                    d0 = fmaf(e5, xq[r][1].y, d0);
                    d0 = fmaf(e6, xq[r][1].z, d0);
                    d0 = fmaf(e7, xq[r][1].w, d0);
                    sA[j][r] = d0;
                }
            }
        }
        #pragma unroll
        for (int j = 0; j < 4; ++j) {
            float cs = esq[j * 256 + t];
            #pragma unroll
            for (int r = 0; r < RB; ++r)
                sA[j][r] = fmaf(-2.0f, sA[j][r], cs);
        }
        // per-row parallel min reduction
        #pragma unroll
        for (int r = 0; r < RB; ++r)
            minsh[r][t] = fminf(fminf(sA[0][r], sA[1][r]), fminf(sA[2][r], sA[3][r]));
        __syncthreads();
        for (int off = 128; off > 0; off >>= 1) {
            if (t < off) {
                #pragma unroll
                for (int r = 0; r < RB; ++r)
                    minsh[r][t] = fminf(minsh[r][t], minsh[r][t + off]);
            }
            __syncthreads();
        }
        if (t < RB) thrsh[t] = minsh[t][0] + SHORTLIST_EPS;
        __syncthreads();
        // shortlist build
        #pragma unroll
        for (int j = 0; j < 4; ++j)
            #pragma unroll
            for (int r = 0; r < RB; ++r)
                if (r < nr && sA[j][r] <= thrsh[r]) {
                    int p = atomicAdd(&scnt[r], 1);
                    if (p < 32) slist[r][p] = j * 256 + t;
                }
        __syncthreads();
        // phase B: thread -> (row r = t>>5, shortlist slot k = t&31)
        {
            int r = t >> 5, k = t & 31;
            int ns = scnt[r] < 32 ? scnt[r] : 32;
            if (r < nr && k < ns) {
                int c = slist[r][k];
                const float4* ec4 = (const float4*)(e + (size_t)c * DIM);
                const float4* xc4 = (const float4*)xsh[r];
                double dot = 0.0;
                #pragma unroll 8
                for (int d4 = 0; d4 < 64; ++d4) {
                    float4 ev = ec4[d4];
                    float4 xv = xc4[d4];
                    dot += (double)ev.x * (double)xv.x + (double)ev.y * (double)xv.y
                         + (double)ev.z * (double)xv.z + (double)ev.w * (double)xv.w;
                }
                float M = (float)dot;
                sres[r][k] = __fsub_rn(__fadd_rn(Ash[r], esq[c]), __fmul_rn(2.0f, M));
            }
        }
        __syncthreads();
        if (t < nr) {
            int ns = scnt[t] < 32 ? scnt[t] : 32;
            float bb = FLT_MAX; int ii = INT_MAX;
            for (int k = 0; k < ns; ++k) {
                float s = sres[t][k]; int c = slist[t][k];
                if (s < bb || (s == bb && c < ii)) { bb = s; ii = c; }
            }
            wsIdx[flagList[base + t]] = ii;
        }
    }
}

// ---- Kernel B: gather quantized + SSE partials + indices + fused final loss ----
// Last-block-done pattern (R4 correctness-proven): writer blocks {plain partial
// store, device fence, atomicAdd(doneCnt)}; the block observing prev==1023
// re-reads all partials via __hip_atomic_load(AGENT) (bypasses non-coherent
// per-XCD L2 - G16) and does the SAME fixed-order reduction as the old
// loss_kernel (bit-identical loss).
__global__ void gather_kernel(const float* __restrict__ x, const float* __restrict__ e,
                              const int* __restrict__ wsIdx, float* __restrict__ out,
                              double* __restrict__ partials, int* __restrict__ doneCnt) {
    const float4* x4 = (const float4*)x;
    const float4* e4 = (const float4*)e;
    float4* q4 = (float4*)out;
    float* outIdx = out + OUT_IDX_OFF;
    const int tid = blockIdx.x * 256 + threadIdx.x;   // 0..262143
    double sse = 0.0;
    #pragma unroll 4
    for (int i = 0; i < 16; ++i) {
        int u = tid + i * 262144;      // float4 unit, 0..4194303
        int row = u >> 6;
        int c4 = u & 63;
        int idx = wsIdx[row];
        float4 q = e4[idx * 64 + c4];
        float4 xv = x4[u];
        q4[u] = q;
        double dx = (double)q.x - (double)xv.x;
        double dy = (double)q.y - (double)xv.y;
        double dz = (double)q.z - (double)xv.z;
        double dw = (double)q.w - (double)xv.w;
        sse += dx * dx + dy * dy + dz * dz + dw * dw;
    }
    if (tid < N_ROWS) outIdx[tid] = (float)wsIdx[tid];
    #pragma unroll
    for (int m = 1; m < 64; m <<= 1) sse += __shfl_xor(sse, m);
    __shared__ double wsum[4];
    __shared__ int lastB;
    if ((threadIdx.x & 63) == 0) wsum[threadIdx.x >> 6] = sse;
    __syncthreads();
    if (threadIdx.x == 0) {
        partials[blockIdx.x] = wsum[0] + wsum[1] + wsum[2] + wsum[3];
        __threadfence();                               // release partial to device
        unsigned prev = atomicAdd((unsigned*)doneCnt, 1u);
        lastB = (prev == (unsigned)(gridDim.x - 1)) ? 1 : 0;
    }
    __syncthreads();
    if (lastB) {
        __shared__ double sh[256];
        const int t = threadIdx.x;
        double s = __hip_atomic_load(&partials[t],       __ATOMIC_RELAXED, __HIP_MEMORY_SCOPE_AGENT)
                 + __hip_atomic_load(&partials[t + 256], __ATOMIC_RELAXED, __HIP_MEMORY_SCOPE_AGENT)
                 + __hip_atomic_load(&partials[t + 512], __ATOMIC_RELAXED, __HIP_MEMORY_SCOPE_AGENT)
                 + __hip_atomic_load(&partials[t + 768], __ATOMIC_RELAXED, __HIP_MEMORY_SCOPE_AGENT);
        sh[t] = s;
        __syncthreads();
        for (int off = 128; off > 0; off >>= 1) {
            if (t < off) sh[t] += sh[t + off];
            __syncthreads();
        }
        if (t == 0) out[OUT_LOSS_OFF] = (float)(0.25 * sh[0] / (double)N_ELEM);
    }
}

extern "C" void kernel_launch(void* const* d_in, const int* in_sizes, int n_in,
                              void* d_out, int out_size, void* d_ws, size_t ws_size,
                              hipStream_t stream) {
    (void)in_sizes; (void)n_in; (void)out_size; (void)ws_size;
    const float* x = (const float*)d_in[0];
    const float* e = (const float*)d_in[1];
    float* out = (float*)d_out;
    char* ws = (char*)d_ws;
    double* partials = (double*)(ws + WS_PARTIALS);
    float* esq = (float*)(ws + WS_ESQ);
    int* wsIdx = (int*)(ws + WS_IDX);
    int* flagCnt = (int*)(ws + WS_FLAGCNT);
    int* doneCnt = (int*)(ws + WS_DONECNT);
    int* flagList = (int*)(ws + WS_FLAGLIST);
    u16* ehi = (u16*)(ws + WS_EHI);
    u16* elo = (u16*)(ws + WS_ELO);
    u16* ehiT = (u16*)(ws + WS_EHIT);

    eprep_kernel<<<260, 256, 0, stream>>>(e, ehi, elo, ehiT, esq, flagCnt, doneCnt);
    argmin_kernel<<<N_ROWS / ROWS_PB, 512, 0, stream>>>(x, ehi, elo, esq,
                                                        wsIdx, flagCnt, flagList);
    rescore_kernel<<<512, 256, 0, stream>>>(x, e, ehiT, esq, wsIdx, flagCnt, flagList);
    gather_kernel<<<1024, 256, 0, stream>>>(x, e, wsIdx, out, partials, doneCnt);
}

// Round 8
// 325.714 us; speedup vs baseline: 1.0355x; 1.0355x over previous
//
#include <hip/hip_runtime.h>
#include <cfloat>
#include <climits>

// Problem constants
#define N_ROWS 65536          // 64*1024 flattened rows
#define DIM 256
#define K_CODES 1024
#define N_ELEM 16777216       // N_ROWS*DIM
#define OUT_LOSS_OFF 16777216
#define OUT_IDX_OFF  16777217

#define ROWS_PB 128           // rows per block (argmin)
#define CT 128                // codes per tile
// Ref computes dists in fp32 with +||x||^2 (~256) -> grid ulp ~3.05e-5; flips
// need exact gap <= ~6.5e-5. Pass-1 (bf16-split MFMA) error ~2e-6..4e-6. Margin
// 1.5e-4 keeps >18x safety. EPS logic needs only |err| << margin - any
// nearest-rounding split qualifies (R5-proven: cvt_pk RNE split, absmax 3.8e-6).
#define EPS_MARGIN 1.5e-4f
#define SHORTLIST_EPS 6e-4f   // covers exact-gap 6.6e-5 + 2*max|x.elo| ~4.2e-4
#define RB 8                  // flagged rows batched per rescore block

// ws layout (bytes)
#define WS_PARTIALS 0         // 1024 double
#define WS_ESQ      8192      // 1024 float
#define WS_IDX      12288     // 65536 int
#define WS_FLAGCNT  274432    // 1 int
#define WS_FLAGLIST 274436    // up to 65536 int -> ends 536580
#define WS_EHI      540672    // 1024*256 u16 = 512 KB (row-major, for argmin)
#define WS_ELO      1064960   // 512 KB
#define WS_EHIT     1589248   // 512 KB q-major transpose (for rescore) -> ends 2113536

typedef unsigned short u16;
typedef __attribute__((ext_vector_type(8))) short bf16x8;
typedef __attribute__((ext_vector_type(4))) float f32x4;
typedef union { bf16x8 v; unsigned u[4]; } frag_u;

// ---- async global->LDS 16B (wave-uniform LDS base + lane*16) ----
__device__ __forceinline__ void glds16(const void* g, void* l) {
    __builtin_amdgcn_global_load_lds(
        (const __attribute__((address_space(1))) unsigned int*)g,
        (__attribute__((address_space(3))) unsigned int*)l,
        16, 0, 0);
}

// ---- packed f32->bf16 RNE (2 elements/op); pure asm (no side effects) ----
__device__ __forceinline__ unsigned cvt_pk_bf16(float lo, float hi) {
    unsigned r;
    asm("v_cvt_pk_bf16_f32 %0, %1, %2" : "=v"(r) : "v"(lo), "v"(hi));
    return r;
}

// ---- exact two-term bf16 split of 8 f32 -> (hi8, lo8) fragments ----
// hi = RNE-bf16(x); lf = x - hi (exact, Sterbenz); lo = RNE-bf16(lf).
__device__ __forceinline__ void split8(float4 a, float4 b, bf16x8& h8, bf16x8& l8) {
    frag_u H, L;
    float f0 = a.x, f1 = a.y, f2 = a.z, f3 = a.w;
    float f4 = b.x, f5 = b.y, f6 = b.z, f7 = b.w;
    const float* f[8] = {&f0,&f1,&f2,&f3,&f4,&f5,&f6,&f7};
    #pragma unroll
    for (int p = 0; p < 4; ++p) {
        float xl = *f[2*p], xh = *f[2*p+1];
        unsigned hw = cvt_pk_bf16(xl, xh);
        float hfl = __uint_as_float(hw << 16);
        float hfh = __uint_as_float(hw & 0xffff0000u);
        H.u[p] = hw;
        L.u[p] = cvt_pk_bf16(xl - hfl, xh - hfh);
    }
    h8 = H.v; l8 = L.v;
}

// ---- exact two-term bf16 split (RN, scalar bit version - eprep only) ----
__device__ __forceinline__ void bsplit(float x, u16& h, u16& l) {
    unsigned u = __float_as_uint(x);
    unsigned hb = (u + 0x7fffu + ((u >> 16) & 1u)) >> 16;
    h = (u16)hb;
    float hf = __uint_as_float(hb << 16);
    float lf = x - hf;                       // exact
    unsigned u2 = __float_as_uint(lf);
    l = (u16)((u2 + 0x7fffu + ((u2 >> 16) & 1u)) >> 16);
}

// ---- numpy fp32 pairwise sum-of-squares over 256 elements (round-3 proven) ----
__device__ __forceinline__ float np_pairwise_sumsq(const float* __restrict__ a) {
    float half[2];
    #pragma unroll
    for (int h = 0; h < 2; ++h) {
        const float* p = a + h * 128;
        float r[8];
        #pragma unroll
        for (int j = 0; j < 8; ++j) r[j] = __fmul_rn(p[j], p[j]);
        for (int i = 8; i < 128; i += 8) {
            #pragma unroll
            for (int j = 0; j < 8; ++j)
                r[j] = __fadd_rn(r[j], __fmul_rn(p[i + j], p[i + j]));
        }
        half[h] = __fadd_rn(__fadd_rn(__fadd_rn(r[0], r[1]), __fadd_rn(r[2], r[3])),
                            __fadd_rn(__fadd_rn(r[4], r[5]), __fadd_rn(r[6], r[7])));
    }
    return __fadd_rn(half[0], half[1]);
}

// ---- fused e-prep: esplit (blocks 0..255) + esq (blocks 256..259) + flag zero ----
// ehiT layout: [qid 0..31][code 0..1023][8 u16], qid = 16B-chunk of the dim axis.
__launch_bounds__(256)
__global__ void eprep_kernel(const float* __restrict__ e, u16* __restrict__ ehi,
                             u16* __restrict__ elo, u16* __restrict__ ehiT,
                             float* __restrict__ esqOut, int* __restrict__ flagCnt) {
    const int b = blockIdx.x;
    if (b < 256) {
        int i4 = b * 256 + threadIdx.x;            // 0..65535
        float4 v = ((const float4*)e)[i4];
        ushort4 h, l;
        bsplit(v.x, h.x, l.x); bsplit(v.y, h.y, l.y);
        bsplit(v.z, h.z, l.z); bsplit(v.w, h.w, l.w);
        ((ushort4*)ehi)[i4] = h;
        ((ushort4*)elo)[i4] = l;
        int c = i4 >> 6;
        int f4 = i4 & 63;
        int qid = f4 >> 1;
        ((ushort4*)ehiT)[((size_t)qid * 1024 + c) * 2 + (f4 & 1)] = h;
    } else {
        if (b == 256 && threadIdx.x == 0) *flagCnt = 0;
        int c = (b - 256) * 256 + threadIdx.x;
        if (c < K_CODES) esqOut[c] = np_pairwise_sumsq(e + c * DIM);
    }
}

// ---------------- Kernel A: split-bf16 MFMA distance + argmin ----------------
// R8: T3+T4 counted-vmcnt double-buffered pipeline at BK=32.
//   - chunk = 128 rows/codes x 32 dims; buffer 32KB; 2 buffers = 64KB (+4KB
//     esqAll) -> STILL 2 blocks/CU (the R3 failure kept BK=64 -> 128KB -> 1/CU).
//   - per chunk, per wave: stage(s+1) {split pv-regs -> ds_write bufN; 2x
//     glds16(e)->bufN; fence; 2 x-loads(s+2)->pv}, compute(s) {12 ds_read_b128,
//     24 MFMA}, then lgkmcnt(0) + vmcnt(2) + RAW s_barrier. vmcnt(2) drains the
//     e-DMA (issued BEFORE compute -> latency hidden under MFMAs) and leaves
//     the 2 x-loads in flight across the barrier. NEVER vmcnt(0) in the loop
//     (that was R3's fatal __syncthreads drain).
//   - FIFO count correctness: per wave outstanding = [eDMA x2 (older), x-load
//     x2 (newer)]; order pinned by compiler fence + sched_barrier(0).
//   - wrapped indices keep all iterations uniform; one vmcnt(0) drain before
//     the merge protects the LDS reuse from the wrapped DMA.
// Swizzle (BK=32, 4 slots/row): LDS slot p of row r holds global 16B-block
// p^((r>>1)&3) -> reads are 2-way bank-aliased (free, m136).
__launch_bounds__(512, 4)
__global__ void argmin_kernel(const float* __restrict__ x,
                              const u16* __restrict__ ehi, const u16* __restrict__ elo,
                              const float* __restrict__ esq, int* __restrict__ wsIdx,
                              int* __restrict__ flagCnt, int* __restrict__ flagList) {
    __shared__ __align__(16) unsigned char lds[65536];   // 2 x 32KB chunk buffers
    __shared__ float esqAll[K_CODES];                    // 4KB, staged once
    // buf b (u16 units, base b*16384): xhi +0, xlo +4096, ehi +8192, elo +12288

    const int t = threadIdx.x;
    const int w = t >> 6;               // wave 0..7
    const int l = t & 63;
    const int lane15 = l & 15;
    const int quad = l >> 4;            // 0..3
    const int rowBase = blockIdx.x * ROWS_PB;
    const int wr = w >> 1;              // 0..3: 32-row group
    const int wc = w & 1;               // 0..1: 64-code group

    float bv[8], sv[8]; int bi[8];
    #pragma unroll
    for (int i = 0; i < 8; ++i) { bv[i] = FLT_MAX; sv[i] = FLT_MAX; bi[i] = INT_MAX; }

    // x staging map: thread t -> row xr=t>>2 (0..127), LDS slot xp=t&3;
    // global block xg = xp ^ ((xr>>1)&3); 8 floats (32B) per thread per chunk.
    const int xr = t >> 2, xp = t & 3;
    const int xg = xp ^ ((xr >> 1) & 3);
    const float* xptr = x + (size_t)(rowBase + xr) * 256 + xg * 8;
    const int xoff = xr * 32 + xp * 8;  // u16 units within an 4096-u16 array

    // e DMA map: wave w covers codes [w*16, w*16+16) per array; lane l ->
    // code ec=w*16+(l>>2), LDS slot ep=l&3, global block eg=ep^((ec>>1)&3).
    // HW writes dst_base + lane*16B == code-major [16 codes][4 slots] exactly.
    const int ec = w * 16 + (l >> 2);
    const int ep = l & 3;
    const int eg = ep ^ ((ec >> 1) & 3);

    u16* ldsU = (u16*)lds;

    // ---------------- prologue ----------------
    esqAll[t] = esq[t];
    esqAll[t + 512] = esq[t + 512];
    float4 pva, pvb;
    {   // x chunk 0 -> regs -> split -> buf0
        const float4* p0 = (const float4*)(xptr + 0);
        pva = p0[0]; pvb = p0[1];
        bf16x8 h8, l8;
        split8(pva, pvb, h8, l8);
        *(bf16x8*)(ldsU + xoff) = h8;
        *(bf16x8*)(ldsU + 4096 + xoff) = l8;
    }
    // e chunk 0 -> buf0
    glds16(ehi + (size_t)ec * 256 + eg * 8, ldsU + 8192 + w * 512);
    glds16(elo + (size_t)ec * 256 + eg * 8, ldsU + 12288 + w * 512);
    asm volatile("" ::: "memory");
    __builtin_amdgcn_sched_barrier(0);
    {   // x chunk 1 prefetch
        const float4* p1 = (const float4*)(xptr + 32);
        pva = p1[0]; pvb = p1[1];
    }
    asm volatile("s_waitcnt lgkmcnt(0)" ::: "memory");
    asm volatile("s_waitcnt vmcnt(2)" ::: "memory");   // eDMA(0) done; x(1) in flight
    __builtin_amdgcn_sched_barrier(0);
    __builtin_amdgcn_s_barrier();

    // ---------------- 64-chunk pipelined loop ----------------
    f32x4 acc[2][4];
    #pragma unroll 2
    for (int s = 0; s < 64; ++s) {
        const int sn = (s + 1) & 63;
        u16* bufC = ldsU + (s & 1) * 16384;
        u16* bufN = ldsU + (sn & 1) * 16384;

        // ---- stage chunk sn into bufN (issue-only; no waits besides pv use) ----
        {
            bf16x8 h8, l8;
            split8(pva, pvb, h8, l8);               // implicit wait: pv loads (1 iter old)
            *(bf16x8*)(bufN + xoff) = h8;
            *(bf16x8*)(bufN + 4096 + xoff) = l8;
        }
        {
            const int ctn = (sn >> 3) * CT;
            const int chn = (sn & 7) * 32;
            glds16(ehi + (size_t)(ctn + ec) * 256 + chn + eg * 8, bufN + 8192 + w * 512);
            glds16(elo + (size_t)(ctn + ec) * 256 + chn + eg * 8, bufN + 12288 + w * 512);
        }
        asm volatile("" ::: "memory");              // pin issue order: eDMA before x
        __builtin_amdgcn_sched_barrier(0);
        {
            const int s2 = (s + 2) & 63;            // x prefetch for chunk s+2
            const float4* p = (const float4*)(xptr + (s2 & 7) * 32);
            pva = p[0]; pvb = p[1];
        }

        // ---- compute chunk s from bufC ----
        if ((s & 7) == 0) {
            #pragma unroll
            for (int ti = 0; ti < 2; ++ti)
                #pragma unroll
                for (int tj = 0; tj < 4; ++tj) acc[ti][tj] = (f32x4){0.f, 0.f, 0.f, 0.f};
        }
        {
            bf16x8 ah[2], al4[2], bh[4], bl[4];
            #pragma unroll
            for (int ti = 0; ti < 2; ++ti) {
                int r = wr * 32 + ti * 16 + lane15;
                int off = r * 32 + ((quad ^ ((r >> 1) & 3)) * 8);
                ah[ti]  = *(const bf16x8*)(bufC + off);
                al4[ti] = *(const bf16x8*)(bufC + 4096 + off);
            }
            #pragma unroll
            for (int tj = 0; tj < 4; ++tj) {
                int c = wc * 64 + tj * 16 + lane15;
                int off = c * 32 + ((quad ^ ((c >> 1) & 3)) * 8);
                bh[tj] = *(const bf16x8*)(bufC + 8192 + off);
                bl[tj] = *(const bf16x8*)(bufC + 12288 + off);
            }
            #pragma unroll
            for (int ti = 0; ti < 2; ++ti)
                #pragma unroll
                for (int tj = 0; tj < 4; ++tj) {
                    acc[ti][tj] = __builtin_amdgcn_mfma_f32_16x16x32_bf16(al4[ti], bh[tj], acc[ti][tj], 0, 0, 0);
                    acc[ti][tj] = __builtin_amdgcn_mfma_f32_16x16x32_bf16(ah[ti], bl[tj], acc[ti][tj], 0, 0, 0);
                    acc[ti][tj] = __builtin_amdgcn_mfma_f32_16x16x32_bf16(ah[ti], bh[tj], acc[ti][tj], 0, 0, 0);
                }
        }
        if ((s & 7) == 7) {
            // epilogue for ct = s>>3 (VALU + esqAll LDS reads; overlaps DMA)
            // s = ||e||^2 - 2*dot. D-layout: row(M)=quad*4+reg, col(N)=lane&15.
            const int ctBase = (s >> 3) * CT;
            #pragma unroll
            for (int tj = 0; tj < 4; ++tj) {
                int cLoc = wc * 64 + tj * 16 + lane15;
                int c = ctBase + cLoc;
                float cs = esqAll[c];
                #pragma unroll
                for (int ti = 0; ti < 2; ++ti)
                    #pragma unroll
                    for (int r4 = 0; r4 < 4; ++r4) {
                        int slot = ti * 4 + r4;
                        float sc = fmaf(-2.0f, acc[ti][tj][r4], cs);
                        if (sc < bv[slot]) {       // candidates ascend in c
                            sv[slot] = bv[slot]; bv[slot] = sc; bi[slot] = c;
                        } else if (sc < sv[slot]) {
                            sv[slot] = sc;
                        }
                    }
            }
        }

        // ---- counted drain + raw barrier (x-loads stay in flight) ----
        asm volatile("s_waitcnt lgkmcnt(0)" ::: "memory");
        asm volatile("s_waitcnt vmcnt(2)" ::: "memory");
        __builtin_amdgcn_sched_barrier(0);
        __builtin_amdgcn_s_barrier();
    }

    // drain wrapped prefetches before LDS reuse by the merge
    asm volatile("s_waitcnt vmcnt(0) lgkmcnt(0)" ::: "memory");
    __builtin_amdgcn_s_barrier();

    // ---- final cross-contributor top-2 merge via LDS (reuses tile memory) ----
    // stride 33 floats: bank = (row+k)%32 -> conflict-free (round-6 proven).
    float* bvA = (float*)lds;                     // [128 rows][33]
    float* svA = (float*)(lds + 16896);
    int*   biA = (int*)(lds + 33792);
    const int contrib = wc * 16 + lane15;         // 0..31
    #pragma unroll
    for (int slot = 0; slot < 8; ++slot) {
        int m = wr * 32 + (slot >> 2) * 16 + quad * 4 + (slot & 3);
        bvA[m * 33 + contrib] = bv[slot];
        svA[m * 33 + contrib] = sv[slot];
        biA[m * 33 + contrib] = bi[slot];
    }
    __syncthreads();

    if (t < ROWS_PB) {
        float bb = FLT_MAX, ss = FLT_MAX;
        int ii = INT_MAX;
        for (int k = 0; k < 32; ++k) {
            float v  = bvA[t * 33 + k];
            int   id = biA[t * 33 + k];
            float s2 = svA[t * 33 + k];
            if (v < bb || (v == bb && id < ii)) {
                ss = fminf(bb, s2);
                bb = v; ii = id;
            } else {
                ss = fminf(ss, v);
            }
        }
        int row = rowBase + t;
        wsIdx[row] = ii;
        if (ss - bb < EPS_MARGIN) {
            int p = atomicAdd(flagCnt, 1);
            flagList[p] = row;
        }
    }
}

// ------- Kernel A2: flagged-row rescore, RB rows batched per block -------
// Phase A: bf16-hi fp32 scores over all 1024 codes via q-major ehiT
// (coalesced; each ehi byte read once per 8 rows) -> per-row shortlist within
// SHORTLIST_EPS of min. Phase B: numpy-emulated quantized score (round-3/4
// proven formula) on shortlist; lexicographic (s, idx) argmin.
__launch_bounds__(256)
__global__ void rescore_kernel(const float* __restrict__ x, const float* __restrict__ e,
                               const u16* __restrict__ ehiT, const float* __restrict__ esq,
                               int* __restrict__ wsIdx, const int* __restrict__ flagCnt,
                               const int* __restrict__ flagList) {
    __shared__ __align__(16) float xsh[RB][DIM];      // 8 KB
    __shared__ float Ash[RB];
    __shared__ float minsh[RB][256];                  // 8 KB
    __shared__ float thrsh[RB];
    __shared__ int scnt[RB];
    __shared__ int slist[RB][32];
    __shared__ float sres[RB][32];
    const int t = threadIdx.x;
    const int cnt = *flagCnt;
    const int ngroups = (cnt + RB - 1) / RB;
    for (int g = blockIdx.x; g < ngroups; g += gridDim.x) {
        const int base = g * RB;
        const int nr = (cnt - base < RB) ? (cnt - base) : RB;
        __syncthreads();                               // protect reuse across groups
        #pragma unroll
        for (int r = 0; r < RB; ++r)
            xsh[r][t] = (r < nr) ? x[(size_t)flagList[base + r] * DIM + t] : 0.0f;
        if (t < RB) scnt[t] = 0;
        __syncthreads();
        if (t < RB) Ash[t] = np_pairwise_sumsq(xsh[t]);

        // phase A: sA[j][r] = dot(x_r, ehi_c), c = j*256+t
        float sA[4][RB];
        #pragma unroll
        for (int j = 0; j < 4; ++j)
            #pragma unroll
            for (int r = 0; r < RB; ++r) sA[j][r] = 0.0f;

        const uint4* eT4 = (const uint4*)ehiT;
        for (int q = 0; q < 32; ++q) {
            float4 xq[RB][2];
            #pragma unroll
            for (int r = 0; r < RB; ++r) {             // broadcast LDS reads
                xq[r][0] = ((const float4*)xsh[r])[2 * q];
                xq[r][1] = ((const float4*)xsh[r])[2 * q + 1];
            }
            #pragma unroll
            for (int j = 0; j < 4; ++j) {
                uint4 uv = eT4[(size_t)q * 1024 + j * 256 + t];   // coalesced
                float e0 = __uint_as_float(uv.x << 16);
                float e1 = __uint_as_float(uv.x & 0xffff0000u);
                float e2 = __uint_as_float(uv.y << 16);
                float e3 = __uint_as_float(uv.y & 0xffff0000u);
                float e4v = __uint_as_float(uv.z << 16);
                float e5 = __uint_as_float(uv.z & 0xffff0000u);
                float e6 = __uint_as_float(uv.w << 16);
                float e7 = __uint_as_float(uv.w & 0xffff0000u);
                #pragma unroll
                for (int r = 0; r < RB; ++r) {
                    float d0 = sA[j][r];
                    d0 = fmaf(e0, xq[r][0].x, d0);
                    d0 = fmaf(e1, xq[r][0].y, d0);
                    d0 = fmaf(e2, xq[r][0].z, d0);
                    d0 = fmaf(e3, xq[r][0].w, d0);
                    d0 = fmaf(e4v, xq[r][1].x, d0);
                    d0 = fmaf(e5, xq[r][1].y, d0);
                    d0 = fmaf(e6, xq[r][1].z, d0);
                    d0 = fmaf(e7, xq[r][1].w, d0);
                    sA[j][r] = d0;
                }
            }
        }
        #pragma unroll
        for (int j = 0; j < 4; ++j) {
            float cs = esq[j * 256 + t];
            #pragma unroll
            for (int r = 0; r < RB; ++r)
                sA[j][r] = fmaf(-2.0f, sA[j][r], cs);
        }
        // per-row parallel min reduction
        #pragma unroll
        for (int r = 0; r < RB; ++r)
            minsh[r][t] = fminf(fminf(sA[0][r], sA[1][r]), fminf(sA[2][r], sA[3][r]));
        __syncthreads();
        for (int off = 128; off > 0; off >>= 1) {
            if (t < off) {
                #pragma unroll
                for (int r = 0; r < RB; ++r)
                    minsh[r][t] = fminf(minsh[r][t], minsh[r][t + off]);
            }
            __syncthreads();
        }
        if (t < RB) thrsh[t] = minsh[t][0] + SHORTLIST_EPS;
        __syncthreads();
        // shortlist build
        #pragma unroll
        for (int j = 0; j < 4; ++j)
            #pragma unroll
            for (int r = 0; r < RB; ++r)
                if (r < nr && sA[j][r] <= thrsh[r]) {
                    int p = atomicAdd(&scnt[r], 1);
                    if (p < 32) slist[r][p] = j * 256 + t;
                }
        __syncthreads();
        // phase B: thread -> (row r = t>>5, shortlist slot k = t&31)
        {
            int r = t >> 5, k = t & 31;
            int ns = scnt[r] < 32 ? scnt[r] : 32;
            if (r < nr && k < ns) {
                int c = slist[r][k];
                const float4* ec4 = (const float4*)(e + (size_t)c * DIM);
                const float4* xc4 = (const float4*)xsh[r];
                double dot = 0.0;
                #pragma unroll 8
                for (int d4 = 0; d4 < 64; ++d4) {
                    float4 ev = ec4[d4];
                    float4 xv = xc4[d4];
                    dot += (double)ev.x * (double)xv.x + (double)ev.y * (double)xv.y
                         + (double)ev.z * (double)xv.z + (double)ev.w * (double)xv.w;
                }
                float M = (float)dot;
                sres[r][k] = __fsub_rn(__fadd_rn(Ash[r], esq[c]), __fmul_rn(2.0f, M));
            }
        }
        __syncthreads();
        if (t < nr) {
            int ns = scnt[t] < 32 ? scnt[t] : 32;
            float bb = FLT_MAX; int ii = INT_MAX;
            for (int k = 0; k < ns; ++k) {
                float s = sres[t][k]; int c = slist[t][k];
                if (s < bb || (s == bb && c < ii)) { bb = s; ii = c; }
            }
            wsIdx[flagList[base + t]] = ii;
        }
    }
}

// ---------------- Kernel B: gather quantized + SSE partials + indices-as-float ----------------
__global__ void gather_kernel(const float* __restrict__ x, const float* __restrict__ e,
                              const int* __restrict__ wsIdx, float* __restrict__ out,
                              double* __restrict__ partials) {
    const float4* x4 = (const float4*)x;
    const float4* e4 = (const float4*)e;
    float4* q4 = (float4*)out;
    float* outIdx = out + OUT_IDX_OFF;
    const int tid = blockIdx.x * 256 + threadIdx.x;   // 0..262143
    double sse = 0.0;
    #pragma unroll 4
    for (int i = 0; i < 16; ++i) {
        int u = tid + i * 262144;      // float4 unit, 0..4194303
        int row = u >> 6;
        int c4 = u & 63;
        int idx = wsIdx[row];
        float4 q = e4[idx * 64 + c4];
        float4 xv = x4[u];
        q4[u] = q;
        double dx = (double)q.x - (double)xv.x;
        double dy = (double)q.y - (double)xv.y;
        double dz = (double)q.z - (double)xv.z;
        double dw = (double)q.w - (double)xv.w;
        sse += dx * dx + dy * dy + dz * dz + dw * dw;
    }
    if (tid < N_ROWS) outIdx[tid] = (float)wsIdx[tid];
    #pragma unroll
    for (int m = 1; m < 64; m <<= 1) sse += __shfl_xor(sse, m);
    __shared__ double wsum[4];
    if ((threadIdx.x & 63) == 0) wsum[threadIdx.x >> 6] = sse;
    __syncthreads();
    if (threadIdx.x == 0)
        partials[blockIdx.x] = wsum[0] + wsum[1] + wsum[2] + wsum[3];
}

// ---------------- Kernel C: final loss reduce ----------------
__global__ void loss_kernel(const double* __restrict__ partials, float* __restrict__ out) {
    __shared__ double sh[256];
    const int t = threadIdx.x;
    double s = partials[t] + partials[t + 256] + partials[t + 512] + partials[t + 768];
    sh[t] = s;
    __syncthreads();
    for (int off = 128; off > 0; off >>= 1) {
        if (t < off) sh[t] += sh[t + off];
        __syncthreads();
    }
    if (t == 0) out[OUT_LOSS_OFF] = (float)(0.25 * sh[0] / (double)N_ELEM);
}

extern "C" void kernel_launch(void* const* d_in, const int* in_sizes, int n_in,
                              void* d_out, int out_size, void* d_ws, size_t ws_size,
                              hipStream_t stream) {
    (void)in_sizes; (void)n_in; (void)out_size; (void)ws_size;
    const float* x = (const float*)d_in[0];
    const float* e = (const float*)d_in[1];
    float* out = (float*)d_out;
    char* ws = (char*)d_ws;
    double* partials = (double*)(ws + WS_PARTIALS);
    float* esq = (float*)(ws + WS_ESQ);
    int* wsIdx = (int*)(ws + WS_IDX);
    int* flagCnt = (int*)(ws + WS_FLAGCNT);
    int* flagList = (int*)(ws + WS_FLAGLIST);
    u16* ehi = (u16*)(ws + WS_EHI);
    u16* elo = (u16*)(ws + WS_ELO);
    u16* ehiT = (u16*)(ws + WS_EHIT);

    eprep_kernel<<<260, 256, 0, stream>>>(e, ehi, elo, ehiT, esq, flagCnt);
    argmin_kernel<<<N_ROWS / ROWS_PB, 512, 0, stream>>>(x, ehi, elo, esq,
                                                        wsIdx, flagCnt, flagList);
    rescore_kernel<<<512, 256, 0, stream>>>(x, e, ehiT, esq, wsIdx, flagCnt, flagList);
    gather_kernel<<<1024, 256, 0, stream>>>(x, e, wsIdx, out, partials);
    loss_kernel<<<1, 256, 0, stream>>>(partials, out);
}

// Round 9
// 289.152 us; speedup vs baseline: 1.1665x; 1.1264x over previous
//
#include <hip/hip_runtime.h>
#include <cfloat>
#include <climits>

// Problem constants
#define N_ROWS 65536          // 64*1024 flattened rows
#define DIM 256
#define K_CODES 1024
#define N_ELEM 16777216       // N_ROWS*DIM
#define OUT_LOSS_OFF 16777216
#define OUT_IDX_OFF  16777217

#define ROWS_PB 128           // rows per block (argmin)
#define CT 128                // codes per tile
// Ref computes dists in fp32 with +||x||^2 (~256) -> grid ulp ~3.05e-5; flips
// need exact gap <= ~6.5e-5. Pass-1 (bf16-split MFMA) error ~2e-6..4e-6. Margin
// 1.5e-4 keeps >18x safety on the flag decision (proven rounds 3-4).
#define EPS_MARGIN 1.5e-4f
// R9: candidate threshold for pass-1-precision shortlist. Ref-winner bound:
// 6.6e-5 (ref noise) + 2x4e-6 (pass-1 err) = 7.4e-5; 1e-4 gives 1.35x safety.
// Superset guarantee: push filter uses the LDS running row-best, which only
// DECREASES -> any-time threshold >= final threshold -> every potential ref
// winner is pushed whenever it is evaluated. Cap overflow -> full exact scan.
#define CAND_TH 1.0e-4f
#define CAND_CAP 24
#define RB 8                  // flagged rows batched per rescore block

// ws layout (bytes)
#define WS_PARTIALS 0         // 1024 double
#define WS_ESQ      8192      // 1024 float
#define WS_IDX      12288     // 65536 int
#define WS_FLAGCNT  274432    // 1 int
#define WS_FLAGLIST 274436    // up to 65536 int -> ends 536580
#define WS_EHI      540672    // 1024*256 u16 = 512 KB (row-major, for argmin)
#define WS_ELO      1064960   // 512 KB -> ends 1589248

typedef unsigned short u16;
typedef __attribute__((ext_vector_type(8))) short bf16x8;
typedef __attribute__((ext_vector_type(4))) float f32x4;
typedef union { bf16x8 v; unsigned u[4]; } frag_u;

// ---- async global->LDS 16B (wave-uniform LDS base + lane*16) ----
__device__ __forceinline__ void glds16(const void* g, void* l) {
    __builtin_amdgcn_global_load_lds(
        (const __attribute__((address_space(1))) unsigned int*)g,
        (__attribute__((address_space(3))) unsigned int*)l,
        16, 0, 0);
}

// ---- packed f32->bf16 RNE (2 elements/op); pure asm (no side effects) ----
__device__ __forceinline__ unsigned cvt_pk_bf16(float lo, float hi) {
    unsigned r;
    asm("v_cvt_pk_bf16_f32 %0, %1, %2" : "=v"(r) : "v"(lo), "v"(hi));
    return r;
}

// ---- exact two-term bf16 split of 8 f32 -> (hi8, lo8) fragments ----
// hi = RNE-bf16(x); lf = x - hi (exact, Sterbenz); lo = RNE-bf16(lf).
__device__ __forceinline__ void split8(float4 a, float4 b, bf16x8& h8, bf16x8& l8) {
    frag_u H, L;
    float f0 = a.x, f1 = a.y, f2 = a.z, f3 = a.w;
    float f4 = b.x, f5 = b.y, f6 = b.z, f7 = b.w;
    const float* f[8] = {&f0,&f1,&f2,&f3,&f4,&f5,&f6,&f7};
    #pragma unroll
    for (int p = 0; p < 4; ++p) {
        float xl = *f[2*p], xh = *f[2*p+1];
        unsigned hw = cvt_pk_bf16(xl, xh);
        float hfl = __uint_as_float(hw << 16);
        float hfh = __uint_as_float(hw & 0xffff0000u);
        H.u[p] = hw;
        L.u[p] = cvt_pk_bf16(xl - hfl, xh - hfh);
    }
    h8 = H.v; l8 = L.v;
}

// ---- exact two-term bf16 split (RN, scalar bit version - eprep only) ----
__device__ __forceinline__ void bsplit(float x, u16& h, u16& l) {
    unsigned u = __float_as_uint(x);
    unsigned hb = (u + 0x7fffu + ((u >> 16) & 1u)) >> 16;
    h = (u16)hb;
    float hf = __uint_as_float(hb << 16);
    float lf = x - hf;                       // exact
    unsigned u2 = __float_as_uint(lf);
    l = (u16)((u2 + 0x7fffu + ((u2 >> 16) & 1u)) >> 16);
}

// ---- ordered-int float mapping (monotone, handles negatives) ----
__device__ __forceinline__ unsigned ford(float f) {
    unsigned u = __float_as_uint(f);
    return (u & 0x80000000u) ? ~u : (u | 0x80000000u);
}
__device__ __forceinline__ float finv(unsigned o) {
    return __uint_as_float((o & 0x80000000u) ? (o ^ 0x80000000u) : ~o);
}

// ---- numpy fp32 pairwise sum-of-squares over 256 elements (round-3 proven) ----
__device__ __forceinline__ float np_pairwise_sumsq(const float* __restrict__ a) {
    float half[2];
    #pragma unroll
    for (int h = 0; h < 2; ++h) {
        const float* p = a + h * 128;
        float r[8];
        #pragma unroll
        for (int j = 0; j < 8; ++j) r[j] = __fmul_rn(p[j], p[j]);
        for (int i = 8; i < 128; i += 8) {
            #pragma unroll
            for (int j = 0; j < 8; ++j)
                r[j] = __fadd_rn(r[j], __fmul_rn(p[i + j], p[i + j]));
        }
        half[h] = __fadd_rn(__fadd_rn(__fadd_rn(r[0], r[1]), __fadd_rn(r[2], r[3])),
                            __fadd_rn(__fadd_rn(r[4], r[5]), __fadd_rn(r[6], r[7])));
    }
    return __fadd_rn(half[0], half[1]);
}

// ---- fused e-prep: esplit (blocks 0..255) + esq (blocks 256..259) + flag zero ----
// R9: ehiT dropped (rescore no longer scans codes).
__launch_bounds__(256)
__global__ void eprep_kernel(const float* __restrict__ e, u16* __restrict__ ehi,
                             u16* __restrict__ elo, float* __restrict__ esqOut,
                             int* __restrict__ flagCnt) {
    const int b = blockIdx.x;
    if (b < 256) {
        int i4 = b * 256 + threadIdx.x;            // 0..65535
        float4 v = ((const float4*)e)[i4];
        ushort4 h, l;
        bsplit(v.x, h.x, l.x); bsplit(v.y, h.y, l.y);
        bsplit(v.z, h.z, l.z); bsplit(v.w, h.w, l.w);
        ((ushort4*)ehi)[i4] = h;
        ((ushort4*)elo)[i4] = l;
    } else {
        if (b == 256 && threadIdx.x == 0) *flagCnt = 0;
        int c = (b - 256) * 256 + threadIdx.x;
        if (c < K_CODES) esqOut[c] = np_pairwise_sumsq(e + c * DIM);
    }
}

// ---------------- Kernel A: split-bf16 MFMA distance + argmin ----------------
// R6-proven schedule (129.5us): 8 waves (512 thr) in 4x2 over a 128x128 tile;
// 2 blocks/CU; in-staging x split via cvt_pk (R6). R3/R8 lesson: do NOT
// pipeline this structure (dbuf and counted-vmcnt both regressed).
// R9 addition: per-row candidate shortlist. Pass-1 scores (err 4e-6) are
// precise enough to shortlist for exact rescore. Per ct, epilogue runs two
// sub-passes: (1) top-2 update + per-slot min -> LDS atomicMin running row
// best (ordered-int); barrier; (2) push codes with s < rowBest + CAND_TH into
// a capped per-row list. Flagged rows export their list; overflow (cnt>24)
// rows get a full exact scan in rescore. LDS: 64K tiles + 13.8K cand = 79.4K
// -> still 2 blocks/CU (<=80K).
__launch_bounds__(512, 4)
__global__ void argmin_kernel(const float* __restrict__ x,
                              const u16* __restrict__ ehi, const u16* __restrict__ elo,
                              const float* __restrict__ esq, int* __restrict__ wsIdx,
                              int* __restrict__ flagCnt, int* __restrict__ flagList,
                              int* __restrict__ wsCand, int* __restrict__ wsCnt) {
    __shared__ __align__(16) unsigned char lds[65536];
    __shared__ float esq_s[CT];
    __shared__ unsigned rowBestOrd[ROWS_PB];
    __shared__ int candCnt[ROWS_PB];
    __shared__ int candList[ROWS_PB][CAND_CAP];
    u16* xhiS = (u16*)lds;              // [128][64] swizzled, 16 KB
    u16* xloS = (u16*)(lds + 16384);
    u16* ehiS = (u16*)(lds + 32768);
    u16* eloS = (u16*)(lds + 49152);

    const int t = threadIdx.x;
    const int w = t >> 6;               // wave 0..7
    const int l = t & 63;
    const int lane15 = l & 15;
    const int quad = l >> 4;            // 0..3
    const int rowBase = blockIdx.x * ROWS_PB;
    const int wr = w >> 1;              // 0..3: 32-row group
    const int wc = w & 1;               // 0..1: 64-code group

    float bv[8], sv[8]; int bi[8];
    #pragma unroll
    for (int i = 0; i < 8; ++i) { bv[i] = FLT_MAX; sv[i] = FLT_MAX; bi[i] = INT_MAX; }

    if (t < ROWS_PB) { rowBestOrd[t] = 0xFFFFFFFFu; candCnt[t] = 0; }

    // e staging roles (glds16): waves 4,5 -> ehi halves, waves 6,7 -> elo halves.
    const int sub8 = l >> 3;            // e: row-in-group-of-8
    const int jb8 = l & 7;              // e: 16B-block slot in 128B row
    const int sb8 = jb8 ^ sub8;         // e: swizzled source block
    const u16* srcE = (w < 6) ? ehi : elo;
    u16* dstE = (w < 6) ? ehiS : eloS;
    const int halfE = w & 1;

    // x staging decomposition: 1024 groups of 8 floats per chunk; 2 per thread.
    const int g0 = t;                   // rows 0..63
    const int g1 = 512 + t;             // rows 64..127
    const int r0 = g0 >> 3, jb0 = g0 & 7, sb0 = jb0 ^ (r0 & 7);
    const int r1 = g1 >> 3, jb1 = g1 & 7, sb1 = jb1 ^ (r1 & 7);

    for (int ct = 0; ct < 8; ++ct) {
        const int ctBase = ct * CT;
        __syncthreads();                          // prior epilogue/LDS reads done
        if (t < CT) esq_s[t] = esq[ctBase + t];

        f32x4 acc[2][4];
        #pragma unroll
        for (int ti = 0; ti < 2; ++ti)
            #pragma unroll
            for (int tj = 0; tj < 4; ++tj) acc[ti][tj] = (f32x4){0.f, 0.f, 0.f, 0.f};

        for (int ch = 0; ch < 4; ++ch) {
            __syncthreads();
            // issue x register loads first, then e DMA
            const float4* gp0 = (const float4*)(x + (size_t)(rowBase + r0) * 256 + ch * 64 + sb0 * 8);
            const float4* gp1 = (const float4*)(x + (size_t)(rowBase + r1) * 256 + ch * 64 + sb1 * 8);
            float4 va0 = gp0[0], vb0 = gp0[1];
            float4 va1 = gp1[0], vb1 = gp1[1];
            if (w >= 4) {
                #pragma unroll
                for (int i = 0; i < 8; ++i) {
                    int r = halfE * 64 + i * 8 + sub8;
                    glds16(srcE + (size_t)(ctBase + r) * 256 + ch * 64 + sb8 * 8,
                           dstE + halfE * 4096 + i * 512);
                }
            }
            {
                bf16x8 h8, l8;
                split8(va0, vb0, h8, l8);
                *(bf16x8*)(xhiS + r0 * 64 + jb0 * 8) = h8;
                *(bf16x8*)(xloS + r0 * 64 + jb0 * 8) = l8;
                split8(va1, vb1, h8, l8);
                *(bf16x8*)(xhiS + r1 * 64 + jb1 * 8) = h8;
                *(bf16x8*)(xloS + r1 * 64 + jb1 * 8) = l8;
            }
            __syncthreads();

            #pragma unroll
            for (int kk = 0; kk < 2; ++kk) {      // two 32-wide k-steps
                bf16x8 ah[2], al4[2], bh[4], bl[4];
                const int blk = kk * 4 + quad;    // 16B-block index in row
                #pragma unroll
                for (int ti = 0; ti < 2; ++ti) {
                    int r = wr * 32 + ti * 16 + lane15;
                    int off = r * 64 + ((blk ^ (r & 7)) * 8);
                    ah[ti]  = *(const bf16x8*)(xhiS + off);
                    al4[ti] = *(const bf16x8*)(xloS + off);
                }
                #pragma unroll
                for (int tj = 0; tj < 4; ++tj) {
                    int r = wc * 64 + tj * 16 + lane15;
                    int off = r * 64 + ((blk ^ (r & 7)) * 8);
                    bh[tj] = *(const bf16x8*)(ehiS + off);
                    bl[tj] = *(const bf16x8*)(eloS + off);
                }
                #pragma unroll
                for (int ti = 0; ti < 2; ++ti)
                    #pragma unroll
                    for (int tj = 0; tj < 4; ++tj) {
                        acc[ti][tj] = __builtin_amdgcn_mfma_f32_16x16x32_bf16(al4[ti], bh[tj], acc[ti][tj], 0, 0, 0);
                        acc[ti][tj] = __builtin_amdgcn_mfma_f32_16x16x32_bf16(ah[ti], bl[tj], acc[ti][tj], 0, 0, 0);
                        acc[ti][tj] = __builtin_amdgcn_mfma_f32_16x16x32_bf16(ah[ti], bh[tj], acc[ti][tj], 0, 0, 0);
                    }
            }
        }

        // ---- epilogue pass 1: top-2 + per-slot min -> LDS row best ----
        // s = ||e||^2 - 2*dot. D-layout: row(M)=quad*4+reg, col(N)=lane&15.
        float sl[8];
        #pragma unroll
        for (int i = 0; i < 8; ++i) sl[i] = FLT_MAX;
        #pragma unroll
        for (int tj = 0; tj < 4; ++tj) {
            int cLoc = wc * 64 + tj * 16 + lane15;
            float cs = esq_s[cLoc];
            int c = ctBase + cLoc;
            #pragma unroll
            for (int ti = 0; ti < 2; ++ti)
                #pragma unroll
                for (int r4 = 0; r4 < 4; ++r4) {
                    int slot = ti * 4 + r4;
                    float s = fmaf(-2.0f, acc[ti][tj][r4], cs);
                    if (s < bv[slot]) {           // candidates ascend in c
                        sv[slot] = bv[slot]; bv[slot] = s; bi[slot] = c;
                    } else if (s < sv[slot]) {
                        sv[slot] = s;
                    }
                    sl[slot] = fminf(sl[slot], s);
                }
        }
        #pragma unroll
        for (int ti = 0; ti < 2; ++ti)
            #pragma unroll
            for (int r4 = 0; r4 < 4; ++r4) {
                int m = wr * 32 + ti * 16 + quad * 4 + r4;
                atomicMin(&rowBestOrd[m], ford(sl[ti * 4 + r4]));
            }
        __syncthreads();
        // ---- epilogue pass 2: candidate pushes vs running row best ----
        #pragma unroll
        for (int ti = 0; ti < 2; ++ti)
            #pragma unroll
            for (int r4 = 0; r4 < 4; ++r4) {
                int m = wr * 32 + ti * 16 + quad * 4 + r4;
                float th = finv(rowBestOrd[m]) + CAND_TH;
                #pragma unroll
                for (int tj = 0; tj < 4; ++tj) {
                    int cLoc = wc * 64 + tj * 16 + lane15;
                    float s = fmaf(-2.0f, acc[ti][tj][r4], esq_s[cLoc]);
                    if (s < th) {
                        int p = atomicAdd(&candCnt[m], 1);
                        if (p < CAND_CAP) candList[m][p] = ctBase + cLoc;
                    }
                }
            }
    }

    // ---- final cross-contributor top-2 merge via LDS (reuses tile memory) ----
    // stride 33 floats: bank = (row+k)%32 -> conflict-free (round-6 proven).
    __syncthreads();
    float* bvA = (float*)lds;                     // [128 rows][33]
    float* svA = (float*)(lds + 16896);
    int*   biA = (int*)(lds + 33792);
    const int contrib = wc * 16 + lane15;         // 0..31
    #pragma unroll
    for (int slot = 0; slot < 8; ++slot) {
        int m = wr * 32 + (slot >> 2) * 16 + quad * 4 + (slot & 3);
        bvA[m * 33 + contrib] = bv[slot];
        svA[m * 33 + contrib] = sv[slot];
        biA[m * 33 + contrib] = bi[slot];
    }
    __syncthreads();

    if (t < ROWS_PB) {
        float bb = FLT_MAX, ss = FLT_MAX;
        int ii = INT_MAX;
        for (int k = 0; k < 32; ++k) {
            float v  = bvA[t * 33 + k];
            int   id = biA[t * 33 + k];
            float s2 = svA[t * 33 + k];
            if (v < bb || (v == bb && id < ii)) {
                ss = fminf(bb, s2);
                bb = v; ii = id;
            } else {
                ss = fminf(ss, v);
            }
        }
        int row = rowBase + t;
        wsIdx[row] = ii;
        if (ss - bb < EPS_MARGIN) {
            int p = atomicAdd(flagCnt, 1);
            flagList[p] = row;
            int cc = candCnt[t];
            wsCnt[row] = cc;
            int n = cc < CAND_CAP ? cc : CAND_CAP;
            for (int k = 0; k < n; ++k) wsCand[row * CAND_CAP + k] = candList[t][k];
        }
    }
}

// ------- Kernel A2: flagged-row exact rescore over argmin's shortlist -------
// R9: Phase A (full 1024-code scan) is GONE - argmin exports per-row candidate
// lists (pass-1 precision, superset-proven). Here: exact numpy-emulated score
// (round-3/4 proven formula, byte-identical) on <=24 candidates per row;
// lexicographic (s, idx) argmin. Overflow rows (cnt>24, ~never): full exact
// scan of all 1024 codes - also a superset, same formula, same winner.
__launch_bounds__(256)
__global__ void rescore_kernel(const float* __restrict__ x, const float* __restrict__ e,
                               const float* __restrict__ esq, int* __restrict__ wsIdx,
                               const int* __restrict__ flagCnt, const int* __restrict__ flagList,
                               const int* __restrict__ wsCand, const int* __restrict__ wsCnt) {
    __shared__ __align__(16) float xsh[RB][DIM];      // 8 KB
    __shared__ float Ash[RB];
    __shared__ int rowsh[RB];
    __shared__ int cntsh[RB];
    __shared__ float sres[RB][CAND_CAP + 8];
    __shared__ float ovS[256];
    __shared__ int ovC[256];
    const int t = threadIdx.x;
    const int cnt = *flagCnt;
    const int ngroups = (cnt + RB - 1) / RB;
    for (int g = blockIdx.x; g < ngroups; g += gridDim.x) {
        const int base = g * RB;
        const int nr = (cnt - base < RB) ? (cnt - base) : RB;
        __syncthreads();                               // protect reuse across groups
        if (t < RB) {
            int row = flagList[base + ((t < nr) ? t : 0)];
            rowsh[t] = row;
            cntsh[t] = (t < nr) ? wsCnt[row] : 0;
        }
        __syncthreads();
        #pragma unroll
        for (int r = 0; r < RB; ++r)
            xsh[r][t] = x[(size_t)rowsh[r] * DIM + t];
        __syncthreads();
        if (t < RB) Ash[t] = np_pairwise_sumsq(xsh[t]);
        __syncthreads();

        // shortlist rows: thread (r = t>>5, k = t&31) exact-scores candidate k
        {
            int r = t >> 5, k = t & 31;
            int nc = (cntsh[r] <= CAND_CAP) ? cntsh[r] : 0;
            if (r < nr && k < nc) {
                int c = wsCand[(size_t)rowsh[r] * CAND_CAP + k];
                const float4* ec4 = (const float4*)(e + (size_t)c * DIM);
                const float4* xc4 = (const float4*)xsh[r];
                double dot = 0.0;
                #pragma unroll 8
                for (int d4 = 0; d4 < 64; ++d4) {
                    float4 ev = ec4[d4];
                    float4 xv = xc4[d4];
                    dot += (double)ev.x * (double)xv.x + (double)ev.y * (double)xv.y
                         + (double)ev.z * (double)xv.z + (double)ev.w * (double)xv.w;
                }
                float M = (float)dot;
                sres[r][k] = __fsub_rn(__fadd_rn(Ash[r], esq[c]), __fmul_rn(2.0f, M));
            }
        }
        __syncthreads();
        if (t < nr && cntsh[t] <= CAND_CAP) {
            int nc = cntsh[t];
            float bb = FLT_MAX; int ii = INT_MAX;
            for (int k = 0; k < nc; ++k) {
                float s = sres[t][k];
                int c = wsCand[(size_t)rowsh[t] * CAND_CAP + k];
                if (s < bb || (s == bb && c < ii)) { bb = s; ii = c; }
            }
            wsIdx[rowsh[t]] = ii;
        }
        // overflow rows: cooperative full exact scan (rare; correctness path)
        for (int r = 0; r < nr; ++r) {
            if (cntsh[r] <= CAND_CAP) continue;
            __syncthreads();
            float bs = FLT_MAX; int bc = INT_MAX;
            for (int j = 0; j < 4; ++j) {
                int c = j * 256 + t;
                const float4* ec4 = (const float4*)(e + (size_t)c * DIM);
                const float4* xc4 = (const float4*)xsh[r];
                double dot = 0.0;
                #pragma unroll 8
                for (int d4 = 0; d4 < 64; ++d4) {
                    float4 ev = ec4[d4];
                    float4 xv = xc4[d4];
                    dot += (double)ev.x * (double)xv.x + (double)ev.y * (double)xv.y
                         + (double)ev.z * (double)xv.z + (double)ev.w * (double)xv.w;
                }
                float M = (float)dot;
                float s = __fsub_rn(__fadd_rn(Ash[r], esq[c]), __fmul_rn(2.0f, M));
                if (s < bs || (s == bs && c < bc)) { bs = s; bc = c; }
            }
            ovS[t] = bs; ovC[t] = bc;
            __syncthreads();
            for (int off = 128; off > 0; off >>= 1) {
                if (t < off) {
                    float s2 = ovS[t + off]; int c2 = ovC[t + off];
                    if (s2 < ovS[t] || (s2 == ovS[t] && c2 < ovC[t])) { ovS[t] = s2; ovC[t] = c2; }
                }
                __syncthreads();
            }
            if (t == 0) wsIdx[rowsh[r]] = ovC[0];
        }
    }
}

// ---------------- Kernel B: gather quantized + SSE partials + indices-as-float ----------------
__global__ void gather_kernel(const float* __restrict__ x, const float* __restrict__ e,
                              const int* __restrict__ wsIdx, float* __restrict__ out,
                              double* __restrict__ partials) {
    const float4* x4 = (const float4*)x;
    const float4* e4 = (const float4*)e;
    float4* q4 = (float4*)out;
    float* outIdx = out + OUT_IDX_OFF;
    const int tid = blockIdx.x * 256 + threadIdx.x;   // 0..262143
    double sse = 0.0;
    #pragma unroll 4
    for (int i = 0; i < 16; ++i) {
        int u = tid + i * 262144;      // float4 unit, 0..4194303
        int row = u >> 6;
        int c4 = u & 63;
        int idx = wsIdx[row];
        float4 q = e4[idx * 64 + c4];
        float4 xv = x4[u];
        q4[u] = q;
        double dx = (double)q.x - (double)xv.x;
        double dy = (double)q.y - (double)xv.y;
        double dz = (double)q.z - (double)xv.z;
        double dw = (double)q.w - (double)xv.w;
        sse += dx * dx + dy * dy + dz * dz + dw * dw;
    }
    if (tid < N_ROWS) outIdx[tid] = (float)wsIdx[tid];
    #pragma unroll
    for (int m = 1; m < 64; m <<= 1) sse += __shfl_xor(sse, m);
    __shared__ double wsum[4];
    if ((threadIdx.x & 63) == 0) wsum[threadIdx.x >> 6] = sse;
    __syncthreads();
    if (threadIdx.x == 0)
        partials[blockIdx.x] = wsum[0] + wsum[1] + wsum[2] + wsum[3];
}

// ---------------- Kernel C: final loss reduce ----------------
__global__ void loss_kernel(const double* __restrict__ partials, float* __restrict__ out) {
    __shared__ double sh[256];
    const int t = threadIdx.x;
    double s = partials[t] + partials[t + 256] + partials[t + 512] + partials[t + 768];
    sh[t] = s;
    __syncthreads();
    for (int off = 128; off > 0; off >>= 1) {
        if (t < off) sh[t] += sh[t + off];
        __syncthreads();
    }
    if (t == 0) out[OUT_LOSS_OFF] = (float)(0.25 * sh[0] / (double)N_ELEM);
}

extern "C" void kernel_launch(void* const* d_in, const int* in_sizes, int n_in,
                              void* d_out, int out_size, void* d_ws, size_t ws_size,
                              hipStream_t stream) {
    (void)in_sizes; (void)n_in; (void)out_size; (void)ws_size;
    const float* x = (const float*)d_in[0];
    const float* e = (const float*)d_in[1];
    float* out = (float*)d_out;
    char* ws = (char*)d_ws;
    double* partials = (double*)(ws + WS_PARTIALS);
    float* esq = (float*)(ws + WS_ESQ);
    int* wsIdx = (int*)(ws + WS_IDX);
    int* flagCnt = (int*)(ws + WS_FLAGCNT);
    int* flagList = (int*)(ws + WS_FLAGLIST);
    u16* ehi = (u16*)(ws + WS_EHI);
    u16* elo = (u16*)(ws + WS_ELO);
    // Candidate lists live in d_out scratch (67 MB): written by argmin, read
    // by rescore, then overwritten by gather (stream-ordered, R1-proven).
    int* wsCand = (int*)d_out;                         // 65536*24 ints = 6.3 MB
    int* wsCnt = wsCand + (size_t)N_ROWS * CAND_CAP;   // 65536 ints

    eprep_kernel<<<260, 256, 0, stream>>>(e, ehi, elo, esq, flagCnt);
    argmin_kernel<<<N_ROWS / ROWS_PB, 512, 0, stream>>>(x, ehi, elo, esq, wsIdx,
                                                        flagCnt, flagList, wsCand, wsCnt);
    rescore_kernel<<<512, 256, 0, stream>>>(x, e, esq, wsIdx, flagCnt, flagList,
                                            wsCand, wsCnt);
    gather_kernel<<<1024, 256, 0, stream>>>(x, e, wsIdx, out, partials);
    loss_kernel<<<1, 256, 0, stream>>>(partials, out);
}